// Round 16
// baseline (190.013 us; speedup 1.0000x reference)
//
#include <hip/hip_runtime.h>
#include <hip/hip_bf16.h>

#define NB 8
#define NC 256
#define NCI 128
#define NPOS 6272   // 8*28*28
#define NM 1568     // 8*14*14
#define PTOT 50176  // 8*6272
#define LOG2E 1.44269504f

typedef __attribute__((ext_vector_type(8))) short bf16x8;
typedef __attribute__((ext_vector_type(4))) float f32x4;
#define MFMA(a,b,c) __builtin_amdgcn_mfma_f32_16x16x32_bf16((a),(b),(c),0,0,0)

__device__ __forceinline__ short f2bf(float f){
  union{float f; unsigned u;} v; v.f=f;
  unsigned r=(v.u + 0x7FFFu + ((v.u>>16)&1u))>>16;
  return (short)r;
}
__device__ __forceinline__ float bf2f(short s){
  union{unsigned u; float f;} v; v.u=((unsigned)(unsigned short)s)<<16; return v.f;
}
__device__ __forceinline__ float exp2v(float x){
  float r; asm("v_exp_f32 %0, %1" : "=v"(r) : "v"(x)); return r;
}
__device__ __forceinline__ unsigned cvtpk(float lo, float hi){
  unsigned r; asm("v_cvt_pk_bf16_f32 %0, %1, %2" : "=v"(r) : "v"(lo), "v"(hi)); return r;
}

// ---------------- weights fp32 -> bf16 (Ww gets hi/lo split) ----------------
__global__ void k_cvt_w(const float* __restrict__ Wt, const float* __restrict__ Wp,
                        const float* __restrict__ Wg, const float* __restrict__ Ww,
                        short* __restrict__ out){
  int i = blockIdx.x*256 + threadIdx.x;   // 131072 total
  if (i < 98304){
    const float* src; int off;
    if (i < 32768)      { src = Wt; off = i; }
    else if (i < 65536) { src = Wp; off = i-32768; }
    else                { src = Wg; off = i-65536; }
    out[i] = f2bf(src[off]);
  } else {
    float v = Ww[i-98304];
    short hi = f2bf(v);
    out[i] = hi;                                  // Ww_hi at [98304,131072)
    out[i+32768] = f2bf(v - bf2f(hi));            // Ww_lo at [131072,163840)
  }
}

// ---------------- fused transpose + 3 projection convs ----------------
__global__ __launch_bounds__(256) void k_tconv(const float* __restrict__ x, const short* __restrict__ Wbf,
                        const float* __restrict__ bt, const float* __restrict__ bp, const float* __restrict__ bg,
                        short* __restrict__ theta, short* __restrict__ phiF, short* __restrict__ gF){
  __shared__ short xt[32*256];   // [pos][c], 16B-granule swizzle: g' = (c>>3) ^ (pos&7)
  int t = threadIdx.x;
  int wv = t >> 6, lane = t & 63;
  int l16 = lane & 15, lg = lane >> 4;
  int b = blockIdx.y, p0 = blockIdx.x*32;
  {
    const float* xr = x + ((size_t)b*NC + t)*NPOS + p0;
    union { float4 q[8]; float f[32]; } u;
    #pragma unroll
    for (int k=0;k<8;k++) u.q[k] = *(const float4*)(xr + k*4);
    int g0 = t >> 3, cb = t & 7;
    #pragma unroll
    for (int pos=0; pos<32; pos++)
      xt[pos*256 + ((g0 ^ (pos&7))<<3) + cb] = f2bf(u.f[pos]);
  }
  __syncthreads();
  bf16x8 a[2][8];
  #pragma unroll
  for (int ms=0;ms<2;ms++)
    #pragma unroll
    for (int ks=0;ks<8;ks++){
      int row = ms*16 + l16;
      a[ms][ks] = *(const bf16x8*)&xt[row*256 + (((ks*4+lg) ^ (row&7))<<3)];
    }
  int n0 = wv*32;
  for (int widx=0; widx<3; widx++){
    const short* Wb = Wbf + widx*32768;
    const float* bias = (widx==0) ? bt : ((widx==1) ? bp : bg);
    short* outp = (widx==0) ? theta : ((widx==1) ? phiF : gF);
    float osc = (widx==0) ? LOG2E : 1.0f;
    float bv[2];
    bv[0] = bias[n0+l16]; bv[1] = bias[n0+16+l16];
    f32x4 acc[2][2] = {};
    #pragma unroll
    for (int ks=0;ks<8;ks++)
      #pragma unroll
      for (int cs=0;cs<2;cs++){
        bf16x8 wf = *(const bf16x8*)&Wb[(n0+cs*16+l16)*NC + ks*32 + lg*8];
        acc[0][cs] = MFMA(a[0][ks], wf, acc[0][cs]);
        acc[1][cs] = MFMA(a[1][ks], wf, acc[1][cs]);
      }
    short* ob = outp + (size_t)b*NPOS*NCI;
    #pragma unroll
    for (int ms=0;ms<2;ms++)
      #pragma unroll
      for (int cs=0;cs<2;cs++)
        #pragma unroll
        for (int j=0;j<4;j++){
          int pos = p0 + ms*16 + lg*4 + j;
          int co  = n0 + cs*16 + l16;
          ob[(size_t)pos*NCI + co] = f2bf((acc[ms][cs][j] + bv[cs])*osc);
        }
  }
}

// ---------------- (1,2,2) max-pool: phiF(pos,128)->phiP(M,128); gF(pos,128)->gP(128,M) ----------------
__global__ void k_pool(const short* __restrict__ phiF, const short* __restrict__ gF,
                       short* __restrict__ phiP, short* __restrict__ gP){
  __shared__ short gb[128][17];
  int b = blockIdx.y, m0 = blockIdx.x*16;
  int lm = threadIdx.x >> 4, cg = threadIdx.x & 15, ci0 = cg*8;
  int m = m0 + lm;
  int tt = m/196, r = m%196, h2 = r/14, w2 = r%14;
  int pbase = tt*784 + h2*56 + w2*2;
  const short* pF  = phiF + (size_t)b*NPOS*NCI;
  const short* gFb = gF   + (size_t)b*NPOS*NCI;
  float pb[8], gv[8];
  #pragma unroll
  for (int i=0;i<8;i++){ pb[i]=-1e30f; gv[i]=-1e30f; }
  #pragma unroll
  for (int dh=0;dh<2;dh++)
    #pragma unroll
    for (int dw=0;dw<2;dw++){
      int pos = pbase + dh*28 + dw;
      bf16x8 v = *(const bf16x8*)&pF[(size_t)pos*NCI+ci0];
      bf16x8 g = *(const bf16x8*)&gFb[(size_t)pos*NCI+ci0];
      #pragma unroll
      for (int i=0;i<8;i++){ pb[i]=fmaxf(pb[i],bf2f(v[i])); gv[i]=fmaxf(gv[i],bf2f(g[i])); }
    }
  bf16x8 po;
  #pragma unroll
  for (int i=0;i<8;i++) po[i]=f2bf(pb[i]);
  *(bf16x8*)&phiP[(size_t)b*NM*NCI + (size_t)m*NCI + ci0] = po;
  #pragma unroll
  for (int i=0;i<8;i++) gb[ci0+i][lm] = f2bf(gv[i]);
  __syncthreads();
  if (threadIdx.x < 128){
    int row = threadIdx.x;
    bf16x8 a, c;
    #pragma unroll
    for (int j=0;j<8;j++){ a[j]=gb[row][j]; c[j]=gb[row][8+j]; }
    short* dst = gP + (size_t)b*NCI*NM + (size_t)row*NM + m0;
    *(bf16x8*)&dst[0] = a;
    *(bf16x8*)&dst[8] = c;
  }
}

// ---------------- flash attention v10 (round-12, passing): v5b loop + swapped-operand Ww GEMM epilogue ----------------
__global__ __launch_bounds__(128,2) void k_attn(const short* __restrict__ theta, const short* __restrict__ phiP,
                       const short* __restrict__ gP, const short* __restrict__ Wwbf,
                       const float* __restrict__ bw, float* __restrict__ wy,
                       float* __restrict__ sum_part, float* __restrict__ sq_part){
  __shared__ __align__(16) char tiles[2][16384];        // loop: [buf][phi 8KB | g 8KB]; epilogue: per-wave yT hi/lo
  __shared__ __align__(16) unsigned pbs[2][2][320];
  int t = threadIdx.x;
  int wv = t >> 6, lane = t & 63;
  int l16 = lane & 15, lg = lane >> 4;
  int b = blockIdx.x & 7, qt = blockIdx.x >> 3;
  int q0 = qt*64 + wv*32;
  const short* th = theta + (size_t)b*NPOS*NCI;
  const char* gph = (const char*)(phiP + (size_t)b*NM*NCI);
  const char* gpg = (const char*)(gP   + (size_t)b*NCI*NM);

  int pr = (t >> 4) & 7, ps = t & 15;
  int gr = t >> 2, gs = t & 3;
  int lw_p[4], lw_g[4]; size_t go_p[4], go_g[4];
  #pragma unroll
  for (int k=0;k<4;k++){
    lw_p[k] = (pr+8*k)*256 + ((ps ^ pr) << 4);
    go_p[k] = (size_t)(pr+8*k)*256 + ps*16;
    lw_g[k] = 8192 + (gr+32*k)*64 + ((gs ^ (gr & 3)) << 4);
    go_g[k] = (size_t)(gr+32*k)*(NM*2) + gs*16;
  }
  int rp[2][4];
  #pragma unroll
  for (int mi=0;mi<2;mi++)
    #pragma unroll
    for (int kc=0;kc<4;kc++)
      rp[mi][kc] = (mi*16+l16)*256 + (((kc*4+lg) ^ (l16 & 7)) << 4);
  int rg[8];
  #pragma unroll
  for (int ct=0;ct<8;ct++)
    rg[ct] = 8192 + (ct*16+l16)*64 + ((lg ^ (l16 & 3)) << 4);

  int lgs01 = (2*lg) & 3, lgs23 = (2*lg+1) & 3;
  int mi2 = (lg >> 1) * 2;
  int rbase = l16*20;

  bf16x8 qf[2][4];
  #pragma unroll
  for (int qi=0;qi<2;qi++)
    #pragma unroll
    for (int kc=0;kc<4;kc++)
      qf[qi][kc] = *(const bf16x8*)&th[(size_t)(q0+qi*16+l16)*NCI + kc*32 + lg*8];
  f32x4 acc[2][8] = {};
  float lsum[2] = {0.f, 0.f};

  {
    uint4 A[8];
    #pragma unroll
    for (int k=0;k<4;k++){ A[k] = *(const uint4*)(gph + go_p[k]); A[4+k] = *(const uint4*)(gpg + go_g[k]); }
    #pragma unroll
    for (int k=0;k<4;k++){ *(uint4*)(tiles[0] + lw_p[k]) = A[k]; *(uint4*)(tiles[0] + lw_g[k]) = A[4+k]; }
  }
  __syncthreads();

  int cur = 0;
  for (int ms=0; ms<49; ms++){
    uint4 A[8];
    if (ms < 48){
      size_t pb_ = (size_t)(ms+1)*8192;
      size_t gb_ = (size_t)(ms+1)*64;
      #pragma unroll
      for (int k=0;k<4;k++){ A[k] = *(const uint4*)(gph + pb_ + go_p[k]); A[4+k] = *(const uint4*)(gpg + gb_ + go_g[k]); }
    }
    const char* L = tiles[cur];
    bf16x8 pf[2][4];
    #pragma unroll
    for (int mi=0;mi<2;mi++)
      #pragma unroll
      for (int kc=0;kc<4;kc++)
        pf[mi][kc] = *(const bf16x8*)(L + rp[mi][kc]);
    f32x4 s[2][2] = {};
    __builtin_amdgcn_s_setprio(1);
    #pragma unroll
    for (int qi=0;qi<2;qi++)
      #pragma unroll
      for (int mi=0;mi<2;mi++)
        #pragma unroll
        for (int kc=0;kc<4;kc++)
          s[qi][mi] = MFMA(pf[mi][kc], qf[qi][kc], s[qi][mi]);
    __builtin_amdgcn_s_setprio(0);
    bf16x8 gf[8];
    #pragma unroll
    for (int ct=0;ct<8;ct++)
      gf[ct] = *(const bf16x8*)(L + rg[ct]);
    #pragma unroll
    for (int qi=0;qi<2;qi++){
      float e0=exp2v(s[qi][0][0]), e1=exp2v(s[qi][0][1]), e2=exp2v(s[qi][0][2]), e3=exp2v(s[qi][0][3]);
      float e4=exp2v(s[qi][1][0]), e5=exp2v(s[qi][1][1]), e6=exp2v(s[qi][1][2]), e7=exp2v(s[qi][1][3]);
      lsum[qi] += (e0+e1)+(e2+e3)+(e4+e5)+(e6+e7);
      uint4 pk;
      pk.x = cvtpk(e0,e1); pk.y = cvtpk(e2,e3); pk.z = cvtpk(e4,e5); pk.w = cvtpk(e6,e7);
      *(uint4*)&pbs[wv][qi][rbase + lg*4] = pk;
    }
    union { unsigned u[4]; bf16x8 v; } pbv[2];
    #pragma unroll
    for (int qi=0;qi<2;qi++){
      pbv[qi].u[0] = pbs[wv][qi][rbase + lgs01*4 + mi2 + 0];
      pbv[qi].u[1] = pbs[wv][qi][rbase + lgs01*4 + mi2 + 1];
      pbv[qi].u[2] = pbs[wv][qi][rbase + lgs23*4 + mi2 + 0];
      pbv[qi].u[3] = pbs[wv][qi][rbase + lgs23*4 + mi2 + 1];
    }
    __builtin_amdgcn_s_setprio(1);
    #pragma unroll
    for (int ct=0;ct<8;ct++){
      acc[0][ct] = MFMA(gf[ct], pbv[0].v, acc[0][ct]);
      acc[1][ct] = MFMA(gf[ct], pbv[1].v, acc[1][ct]);
    }
    __builtin_amdgcn_s_setprio(0);
    if (ms < 48){
      char* D = tiles[cur^1];
      #pragma unroll
      for (int k=0;k<4;k++){ *(uint4*)(D + lw_p[k]) = A[k]; *(uint4*)(D + lw_g[k]) = A[4+k]; }
    }
    __syncthreads();
    cur ^= 1;
  }

  // ---- epilogue: normalize, hi/lo split into per-wave LDS as [q][ci] frag tiles ----
  float inv[2];
  #pragma unroll
  for (int qi=0;qi<2;qi++){
    float v = lsum[qi];
    v += __shfl_xor(v, 16); v += __shfl_xor(v, 32);
    inv[qi] = 1.f / v;
  }
  {
    char* Y = tiles[0] + wv*16384;          // 8KB hi | 8KB lo
    #pragma unroll
    for (int qi=0;qi<2;qi++){
      int q = qi*16 + l16;
      int rowoff = q*256 + ((lg&1)<<3);
      #pragma unroll
      for (int ct=0;ct<8;ct++){
        float v0 = acc[qi][ct][0]*inv[qi];
        float v1 = acc[qi][ct][1]*inv[qi];
        float v2 = acc[qi][ct][2]*inv[qi];
        float v3 = acc[qi][ct][3]*inv[qi];
        unsigned h0 = cvtpk(v0,v1), h1 = cvtpk(v2,v3);
        float l0 = v0 - bf2f((short)(h0 & 0xffff));
        float l1 = v1 - bf2f((short)(h0 >> 16));
        float l2 = v2 - bf2f((short)(h1 & 0xffff));
        float l3 = v3 - bf2f((short)(h1 >> 16));
        unsigned o0 = cvtpk(l0,l1), o1 = cvtpk(l2,l3);
        int g = ct*2 + (lg>>1);
        int off = rowoff + (((g ^ (q&7))) << 4);
        uint2 hv; hv.x = h0; hv.y = h1;
        uint2 lv; lv.x = o0; lv.y = o1;
        *(uint2*)(Y + off) = hv;
        *(uint2*)(Y + 8192 + off) = lv;
      }
    }
  }
  __syncthreads();
  // y frags back from LDS (A-operand: rows = q = l16, k = ci contiguous)
  bf16x8 bhi[2][4], blo[2][4];
  {
    const char* Y = tiles[0] + wv*16384;
    #pragma unroll
    for (int qi=0;qi<2;qi++)
      #pragma unroll
      for (int kc=0;kc<4;kc++){
        int off = (qi*16+l16)*256 + ((((kc*4+lg) ^ (l16&7))) << 4);
        bhi[qi][kc] = *(const bf16x8*)(Y + off);
        blo[qi][kc] = *(const bf16x8*)(Y + 8192 + off);
      }
  }
  // Ww GEMM (hi/lo), SWAPPED operands: D row = pos, col = ch -> float4 wy stores
  const short* Whi = Wwbf;
  const short* Wlo = Wwbf + 32768;
  int slot = blockIdx.x*2 + wv;             // [0,1568)
  #pragma unroll 2
  for (int cht=0; cht<16; cht++){
    bf16x8 ahi[4], alo[4];
    #pragma unroll
    for (int kc=0;kc<4;kc++){
      ahi[kc] = *(const bf16x8*)&Whi[(cht*16+l16)*NCI + kc*32 + lg*8];
      alo[kc] = *(const bf16x8*)&Wlo[(cht*16+l16)*NCI + kc*32 + lg*8];
    }
    f32x4 e[2] = {};
    #pragma unroll
    for (int kc=0;kc<4;kc++){
      e[0] = MFMA(bhi[0][kc], ahi[kc], e[0]);
      e[0] = MFMA(blo[0][kc], ahi[kc], e[0]);
      e[0] = MFMA(bhi[0][kc], alo[kc], e[0]);
      e[1] = MFMA(bhi[1][kc], ahi[kc], e[1]);
      e[1] = MFMA(blo[1][kc], ahi[kc], e[1]);
      e[1] = MFMA(bhi[1][kc], alo[kc], e[1]);
    }
    int ch = cht*16 + l16;
    float bwv = bw[ch];
    float sv = 0.f, qv = 0.f;
    size_t chbase = ((size_t)b*NC + ch)*NPOS;
    #pragma unroll
    for (int qi=0;qi<2;qi++){
      float4 w4;
      float v0 = e[qi][0] + bwv, v1 = e[qi][1] + bwv, v2 = e[qi][2] + bwv, v3 = e[qi][3] + bwv;
      w4.x = v0; w4.y = v1; w4.z = v2; w4.w = v3;
      *(float4*)&wy[chbase + q0 + qi*16 + lg*4] = w4;
      sv += (v0+v1)+(v2+v3);
      qv += (v0*v0+v1*v1)+(v2*v2+v3*v3);
    }
    sv += __shfl_xor(sv,16); sv += __shfl_xor(sv,32);
    qv += __shfl_xor(qv,16); qv += __shfl_xor(qv,32);
    if (lg==0){
      sum_part[ch*1568 + slot] = sv;
      sq_part [ch*1568 + slot] = qv;
    }
  }
}

__global__ void k_finstats(const float* __restrict__ sum_part, const float* __restrict__ sq_part,
                           const float* __restrict__ gamma, const float* __restrict__ beta,
                           float* __restrict__ scale, float* __restrict__ shift){
  __shared__ float r[4][2];
  int c = blockIdx.x;
  int t = threadIdx.x, wv = t>>6;
  float s=0.f, q=0.f;
  for (int k=t; k<1568; k+=256){ s += sum_part[c*1568+k]; q += sq_part[c*1568+k]; }
  #pragma unroll
  for (int off=1; off<64; off<<=1){ s += __shfl_xor(s,off); q += __shfl_xor(q,off); }
  if ((t&63)==0){ r[wv][0]=s; r[wv][1]=q; }
  __syncthreads();
  if (t==0){
    s = r[0][0]+r[1][0]+r[2][0]+r[3][0];
    q = r[0][1]+r[1][1]+r[2][1]+r[3][1];
    float mean = s*(1.f/PTOT);
    float var  = fmaxf(q*(1.f/PTOT) - mean*mean, 0.f);
    float rs = rsqrtf(var + 1e-5f);
    float sc = gamma[c]*rs;
    scale[c]=sc; shift[c]=beta[c]-mean*sc;
  }
}

// ---------------- elementwise: out = wy*scale + shift + x ----------------
__global__ __launch_bounds__(256) void k_out(const float* __restrict__ wy, const float* __restrict__ scale,
                      const float* __restrict__ shift, const float* __restrict__ x, float* __restrict__ out){
  int bid = blockIdx.x;                     // b*NC + ch
  int ch = bid & 255;
  float scv = scale[ch], shv = shift[ch];
  size_t base = (size_t)bid * NPOS;
  const float4* w4 = (const float4*)(wy + base);
  const float4* x4 = (const float4*)(x + base);
  float4* o4 = (float4*)(out + base);
  for (int k = threadIdx.x; k < NPOS/4; k += 256){
    float4 w = w4[k], xx = x4[k];
    float4 r;
    r.x = w.x*scv + shv + xx.x;
    r.y = w.y*scv + shv + xx.y;
    r.z = w.z*scv + shv + xx.z;
    r.w = w.w*scv + shv + xx.w;
    o4[k] = r;
  }
}

extern "C" void kernel_launch(void* const* d_in, const int* in_sizes, int n_in,
                              void* d_out, int out_size, void* d_ws, size_t ws_size,
                              hipStream_t stream){
  const float* x     = (const float*)d_in[0];
  const float* Wg    = (const float*)d_in[1];
  const float* bg    = (const float*)d_in[2];
  const float* Wt    = (const float*)d_in[3];
  const float* bt    = (const float*)d_in[4];
  const float* Wp    = (const float*)d_in[5];
  const float* bp    = (const float*)d_in[6];
  const float* Ww    = (const float*)d_in[7];
  const float* bw    = (const float*)d_in[8];
  const float* gamma = (const float*)d_in[9];
  const float* beta  = (const float*)d_in[10];
  float* out = (float*)d_out;

  char* w = (char*)d_ws;
  short* Wbf   = (short*)w;                           // 327,680 B (Wt,Wp,Wg,Ww_hi,Ww_lo)
  short* theta = (short*)(w + 327680);                // 12,845,056  (read by attn)
  short* phiP  = (short*)(w + 13172736);              //  3,211,264  (read by attn)
  short* gP    = (short*)(w + 16384000);              //  3,211,264  (read by attn)
  short* phiF  = (short*)(w + 19595264);              // 12,845,056  (dead after pool)
  short* gF    = (short*)(w + 32440320);              // 12,845,056  (dead after pool)
  float* wy    = (float*)(w + 19595264);              // 51,380,224  (overlaps phiF+gF+fresh)
  float* sum_part = (float*)(w + 70975488);           //  1,605,632
  float* sq_part  = (float*)(w + 72581120);           //  1,605,632
  float* scale    = (float*)(w + 74186752);           //  1,024
  float* shift    = (float*)(w + 74187776);           //  1,024

  k_cvt_w<<<dim3(512),256,0,stream>>>(Wt,Wp,Wg,Ww,Wbf);
  k_tconv<<<dim3(196,8),256,0,stream>>>(x,Wbf,bt,bp,bg,theta,phiF,gF);
  k_pool<<<dim3(98,8),256,0,stream>>>(phiF,gF,phiP,gP);
  const short* Wwbf = Wbf + 98304;
  k_attn<<<dim3(784),128,0,stream>>>(theta,phiP,gP,Wwbf,bw,wy,sum_part,sq_part);
  k_finstats<<<dim3(256),256,0,stream>>>(sum_part,sq_part,gamma,beta,scale,shift);
  k_out<<<dim3(2048),256,0,stream>>>(wy,scale,shift,x,out);
}